// Round 8
// baseline (135.096 us; speedup 1.0000x reference)
//
#include <hip/hip_runtime.h>

// R8: R7 structure (s_load weights, no LDS, packed fp32, exp2-domain,
// Montgomery-batched sigmoid rcps) with ROWS=1 and __launch_bounds__(256,8):
// 8192 waves -> 8 resident waves/SIMD (vs 4 at ROWS=2).
// Rationale: VALUBusy=67% at R7 proves v_exp_f32 holds the issue port ~16cy
// (else busy would read ~22%); remaining 33% idle = windows where all 4
// resident waves sit in their per-iteration serial tails (exp->sum->rcp->w).
// R1 (only prior 8-wave config with scalar-pipe weights) hit 0.71 issue
// efficiency — best observed. This tests the TLP lever on the current
// structure with everything else held fixed.

typedef float v2f __attribute__((ext_vector_type(2)));

#define LOG2E 1.44269504088896340736f

__device__ __forceinline__ float rcpf(float a) { return __builtin_amdgcn_rcpf(a); }

#if __has_builtin(__builtin_amdgcn_exp2f)
__device__ __forceinline__ float exp2_fast(float a) { return __builtin_amdgcn_exp2f(a); }
#else
__device__ __forceinline__ float exp2_fast(float a) { return __expf(0.6931471805599453f * a); }
#endif

__global__ __launch_bounds__(256, 8) void fused_attn_mlp(
    const float* __restrict__ x,
    const float* __restrict__ wq,
    const float* __restrict__ wk,
    const float* __restrict__ wv,
    const float* __restrict__ Wh,
    const float* __restrict__ bh,
    const float* __restrict__ Wo,
    const float* __restrict__ bo,
    float* __restrict__ out,
    int B)
{
    const int b = blockIdx.x * blockDim.x + threadIdx.x;
    if (b >= B) return;

    // ---- load x row: 4x float4, issued first ----
    float xs[16];
    v2f xv2[8];
    {
        const float4* xr = reinterpret_cast<const float4*>(x) + (size_t)b * 4;
        float4 a0 = xr[0], a1 = xr[1], a2 = xr[2], a3 = xr[3];
        xs[0]=a0.x; xs[1]=a0.y; xs[2]=a0.z; xs[3]=a0.w;
        xs[4]=a1.x; xs[5]=a1.y; xs[6]=a1.z; xs[7]=a1.w;
        xs[8]=a2.x; xs[9]=a2.y; xs[10]=a2.z; xs[11]=a2.w;
        xs[12]=a3.x; xs[13]=a3.y; xs[14]=a3.z; xs[15]=a3.w;
        #pragma unroll
        for (int p = 0; p < 8; ++p) { v2f v; v[0]=xs[2*p]; v[1]=xs[2*p+1]; xv2[p]=v; }
    }

    // ---- attention block 1 (D=16), exp2 domain ----
    const float kq1 = wk[0] * wq[0] * LOG2E;
    const float v1  = wv[0];

    float xmx = xs[0], xmn = xs[0];
    #pragma unroll
    for (int i = 1; i < 16; ++i) { xmx = fmaxf(xmx, xs[i]); xmn = fminf(xmn, xs[i]); }

    v2f o1v[8];
    #pragma unroll
    for (int p = 0; p < 8; ++p) o1v[p] = (v2f)(0.f);

    #pragma unroll
    for (int i = 0; i < 16; ++i) {
        const float c = kq1 * xs[i];
        const float m = fmaxf(c * xmx, c * xmn);   // exact attained max -> args <= 0
        v2f cc; cc[0]=c; cc[1]=c;
        v2f mm; mm[0]=m; mm[1]=m;
        v2f e2[8];
        #pragma unroll
        for (int p = 0; p < 8; ++p) {
            v2f a = cc * xv2[p] - mm;              // v_pk_fma_f32
            v2f e; e[0] = exp2_fast(a[0]); e[1] = exp2_fast(a[1]);
            e2[p] = e;
        }
        v2f s01 = e2[0] + e2[1];
        v2f s23 = e2[2] + e2[3];
        v2f s45 = e2[4] + e2[5];
        v2f s67 = e2[6] + e2[7];
        v2f sv  = (s01 + s23) + (s45 + s67);
        const float w = v1 * xs[i] * rcpf(sv[0] + sv[1]);
        v2f ww; ww[0]=w; ww[1]=w;
        #pragma unroll
        for (int p = 0; p < 8; ++p) o1v[p] += ww * e2[p];
    }

    // ---- fused MLP: 16 -> 64 sigmoid -> 8. Uniform-index weight reads ->
    //      s_load (scalar pipe). Sigmoid rcps Montgomery-batched (groups of 4). ----
    v2f x2v[4];
    #pragma unroll
    for (int p = 0; p < 4; ++p) { v2f v; v[0]=bo[2*p]; v[1]=bo[2*p+1]; x2v[p]=v; }

    const v2f* Wh2 = reinterpret_cast<const v2f*>(Wh);   // [64][8] pairs

    #pragma unroll 2
    for (int g = 0; g < 16; ++g) {
        float apre[4];
        #pragma unroll
        for (int hh = 0; hh < 4; ++hh) {
            const int h = g * 4 + hh;
            v2f acc = Wh2[h * 8 + 0] * o1v[0];
            #pragma unroll
            for (int p = 1; p < 8; ++p) acc += Wh2[h * 8 + p] * o1v[p];
            apre[hh] = acc[0] + acc[1] + bh[h];
        }
        // clamp inert for a > -20.8 (sigma < 1e-9 there); keeps
        // d = 1+2^la <= 1+2^30 so prod4 <= 2^121 (no overflow).
        float d[4];
        #pragma unroll
        for (int hh = 0; hh < 4; ++hh) {
            const float la = fminf(-apre[hh] * LOG2E, 30.f);
            d[hh] = 1.f + exp2_fast(la);
        }
        const float p01  = d[0] * d[1];
        const float p012 = p01 * d[2];
        const float rq   = rcpf(p012 * d[3]);
        const float i3 = rq * p012;
        const float tq = rq * d[3];      // 1/(d0 d1 d2)
        const float i2 = tq * p01;
        const float t2 = tq * d[2];      // 1/(d0 d1)
        float sg[4];
        sg[0] = t2 * d[1];
        sg[1] = t2 * d[0];
        sg[2] = i2;
        sg[3] = i3;

        #pragma unroll
        for (int hh = 0; hh < 4; ++hh) {
            const int h = g * 4 + hh;
            v2f sgv; sgv[0] = sg[hh]; sgv[1] = sg[hh];
            #pragma unroll
            for (int p = 0; p < 4; ++p) {
                v2f wo2;
                wo2[0] = Wo[(2 * p) * 64 + h];       // uniform -> s_load
                wo2[1] = Wo[(2 * p + 1) * 64 + h];
                x2v[p] += wo2 * sgv;
            }
        }
    }

    // ---- attention block 2 (D=8), exp2 domain; LOG2E folded into o2 ----
    const float kq2 = wk[1] * wq[1] * LOG2E;
    const float v2s = wv[1] * LOG2E;

    float ys[8];
    #pragma unroll
    for (int i = 0; i < 8; ++i) ys[i] = x2v[i >> 1][i & 1];
    float ymx = ys[0], ymn = ys[0];
    #pragma unroll
    for (int i = 1; i < 8; ++i) { ymx = fmaxf(ymx, ys[i]); ymn = fminf(ymn, ys[i]); }

    v2f o2v[4];
    #pragma unroll
    for (int p = 0; p < 4; ++p) o2v[p] = (v2f)(0.f);

    #pragma unroll
    for (int i = 0; i < 8; ++i) {
        const float c = kq2 * ys[i];
        const float m = fmaxf(c * ymx, c * ymn);
        v2f cc; cc[0]=c; cc[1]=c;
        v2f mm; mm[0]=m; mm[1]=m;
        v2f e2[4];
        #pragma unroll
        for (int p = 0; p < 4; ++p) {
            v2f a = cc * x2v[p] - mm;
            v2f e; e[0] = exp2_fast(a[0]); e[1] = exp2_fast(a[1]);
            e2[p] = e;
        }
        v2f sv = (e2[0] + e2[1]) + (e2[2] + e2[3]);
        const float w = v2s * ys[i] * rcpf(sv[0] + sv[1]);
        v2f ww; ww[0]=w; ww[1]=w;
        #pragma unroll
        for (int p = 0; p < 4; ++p) o2v[p] += ww * e2[p];
    }

    // ---- final softmax (log2 domain) + dot with x[8:16] ----
    float o2s[8];
    #pragma unroll
    for (int i = 0; i < 8; ++i) o2s[i] = o2v[i >> 1][i & 1];
    float m2 = o2s[0];
    #pragma unroll
    for (int i = 1; i < 8; ++i) m2 = fmaxf(m2, o2s[i]);
    v2f mm2; mm2[0]=m2; mm2[1]=m2;
    v2f se = (v2f)(0.f), de = (v2f)(0.f);
    #pragma unroll
    for (int p = 0; p < 4; ++p) {
        v2f a = o2v[p] - mm2;
        v2f e; e[0] = exp2_fast(a[0]); e[1] = exp2_fast(a[1]);
        se += e;
        v2f xp; xp[0]=xs[8+2*p]; xp[1]=xs[9+2*p];
        de += xp * e;
    }
    out[b] = (de[0] + de[1]) * rcpf(se[0] + se[1]);
}

extern "C" void kernel_launch(void* const* d_in, const int* in_sizes, int n_in,
                              void* d_out, int out_size, void* d_ws, size_t ws_size,
                              hipStream_t stream) {
    const float* x  = (const float*)d_in[0];
    const float* wq = (const float*)d_in[1];
    const float* wk = (const float*)d_in[2];
    const float* wv = (const float*)d_in[3];
    const float* Wh = (const float*)d_in[4];
    const float* bh = (const float*)d_in[5];
    const float* Wo = (const float*)d_in[6];
    const float* bo = (const float*)d_in[7];
    float* out = (float*)d_out;

    const int B = in_sizes[0] / 16;
    const int block = 256;
    const int grid = (B + block - 1) / block;
    fused_attn_mlp<<<grid, block, 0, stream>>>(x, wq, wk, wv, Wh, bh, Wo, bo, out, B);
}